// Round 3
// baseline (410.769 us; speedup 1.0000x reference)
//
#include <hip/hip_runtime.h>
#include <hip/hip_bf16.h>

// ---------- types ----------
typedef __bf16 bf16x8 __attribute__((ext_vector_type(8)));
typedef float  f32x4  __attribute__((ext_vector_type(4)));

#define H_DIM 112
#define W_DIM 112
#define CIN 64
#define CMID 192          // 3*64
#define COUT 128
#define NB 16

// ---------------------------------------------------------------
// Kernel A: repack weights [co][ci][kh][kw] fp32 -> [khw][co][ci] bf16
// ---------------------------------------------------------------
__global__ __launch_bounds__(256) void repack_w_kernel(
    const float* __restrict__ w, __hip_bfloat16* __restrict__ wr)
{
    int idx = blockIdx.x * 256 + threadIdx.x;
    if (idx < 9 * COUT * CMID) {
        int ci  = idx % CMID;
        int t   = idx / CMID;
        int co  = t % COUT;
        int khw = t / COUT;
        wr[idx] = __float2bfloat16(w[(co * CMID + ci) * 9 + khw]);
    }
}

// ---------------------------------------------------------------
// Kernel B: bilinear shift + Maclaurin powers -> y NHWC bf16
// y layout: [n][h][w][c3], c3 = c + 64*(power-1), shape (16,112,112,192)
// ILP version: params cached in LDS, clamped unconditional loads * mask,
// 4 channels batched per chunk -> ~32 loads in flight.
// ---------------------------------------------------------------
#define TSTRIDE 196   // 192 + 4 pad (98 dwords => stride 2 mod 32 banks)

__global__ __launch_bounds__(256) void shift_pow_kernel(
    const float* __restrict__ x, const float* __restrict__ shifts,
    __hip_bfloat16* __restrict__ y)
{
    __shared__ __hip_bfloat16 tile[W_DIM * TSTRIDE];   // 43,904 B
    __shared__ float4 prm[CIN];                        // (fx, fy, wx, wy)

    const int n   = blockIdx.y;
    const int h   = blockIdx.x;
    const int tid = threadIdx.x;
    const int wl  = tid & 63;
    const int c0  = tid >> 6;   // 0..3

    if (tid < CIN) {
        float sx = shifts[2 * tid]     * 4.0f;
        float sy = shifts[2 * tid + 1] * 4.0f;
        float fx = floorf(sx), fy = floorf(sy);
        prm[tid] = make_float4(fx, fy, sx - fx, sy - fy);
    }
    __syncthreads();

    for (int cc = 0; cc < 16; cc += 4) {
        #pragma unroll
        for (int u = 0; u < 4; ++u) {
            const int c = c0 + 4 * (cc + u);
            float4 p = prm[c];
            int ix = (int)p.x, iy = (int)p.y;
            float wx = p.z, wy = p.w;
            int r0 = h + iy, r1 = r0 + 1;
            bool r0v = (unsigned)r0 < (unsigned)H_DIM;
            bool r1v = (unsigned)r1 < (unsigned)H_DIM;
            int rr0 = min(max(r0, 0), H_DIM - 1);
            int rr1 = min(max(r1, 0), H_DIM - 1);
            const float* xp  = x + ((size_t)(n * CIN + c) * H_DIM) * W_DIM;
            const float* xr0 = xp + rr0 * W_DIM;
            const float* xr1 = xp + rr1 * W_DIM;

            #pragma unroll
            for (int wb = 0; wb < 2; ++wb) {
                int px  = wb * 64 + wl;
                int cl0 = px + ix, cl1 = cl0 + 1;
                bool c0v = (unsigned)cl0 < (unsigned)W_DIM;
                bool c1v = (unsigned)cl1 < (unsigned)W_DIM;
                int a0 = min(max(cl0, 0), W_DIM - 1);
                int a1 = min(max(cl1, 0), W_DIM - 1);
                float f00 = (r0v && c0v) ? 1.0f : 0.0f;
                float f01 = (r0v && c1v) ? 1.0f : 0.0f;
                float f10 = (r1v && c0v) ? 1.0f : 0.0f;
                float f11 = (r1v && c1v) ? 1.0f : 0.0f;
                // unconditional (clamped) loads -> good batching
                float t00 = xr0[a0] * f00;
                float t01 = xr0[a1] * f01;
                float t10 = xr1[a0] * f10;
                float t11 = xr1[a1] * f11;
                float v  = (1.0f - wy) * ((1.0f - wx) * t00 + wx * t01)
                         +         wy  * ((1.0f - wx) * t10 + wx * t11);
                float v2 = v * v;
                float v3 = v2 * v;
                if (px < W_DIM) {
                    __hip_bfloat16* tp = &tile[px * TSTRIDE];
                    tp[c]       = __float2bfloat16(v);
                    tp[c + 64]  = __float2bfloat16(v2);
                    tp[c + 128] = __float2bfloat16(v3);
                }
            }
        }
    }
    __syncthreads();

    // coalesced write-out: 112 px * 96 dwords = 10752 dwords, 42 iters * 256 thr
    const unsigned* tl = (const unsigned*)tile;
    unsigned* yo = (unsigned*)(y + ((size_t)(n * H_DIM + h) * W_DIM) * CMID);
    #pragma unroll 2
    for (int it = 0; it < 42; ++it) {
        int idx = it * 256 + tid;
        int px  = idx / 96;
        int cp  = idx - px * 96;
        yo[idx] = tl[px * 98 + cp];
    }
}

// ---------------------------------------------------------------
// Kernel C: implicit-GEMM 3x3 conv, bf16 MFMA 16x16x32.
// Software-pipelined: K split in halves of 96 ch; 2 LDS buffers
// (114 x 104 elem each, 47.4 KB total); prefetch step s+1 into regs
// while computing step s; ONE barrier per step.
// Block = 128 co x 112 px (one row), wave = 32 co x 112 px (mt=2, nt=7).
// ---------------------------------------------------------------
#define YSTR 104            // 96 ch + 8 pad elements; 208 B => 52 dw = 20 mod 32 banks
#define BUFSZ (114 * YSTR)

__global__ __launch_bounds__(256, 3) void conv_kernel(
    const __bf16* __restrict__ y,    // [16][112][112][192]
    const __bf16* __restrict__ wr,   // [9][128][192]
    const float* __restrict__ bias,
    float* __restrict__ out)         // [16][128][112][112]
{
    __shared__ __align__(16) __bf16 ybuf[2][BUFSZ];   // 47,424 B

    const int tid  = threadIdx.x;
    const int lane = tid & 63;
    const int wid  = tid >> 6;     // 0..3 -> co block of 32
    const int m    = lane & 15;
    const int quad = lane >> 4;

    const int h = blockIdx.x;
    const int n = blockIdx.y;

    // zero halo slots (px slot 0 and 113) of both buffers: 2*2*52 = 208 dwords
    if (tid < 208) {
        int b    = tid >= 104;
        int r    = tid - b * 104;
        int slot = (r >= 52) ? 113 : 0;
        int dw   = (r >= 52) ? r - 52 : r;
        ((unsigned*)&ybuf[b][slot * YSTR])[dw] = 0u;
    }

    f32x4 acc[2][7];
    #pragma unroll
    for (int mt = 0; mt < 2; ++mt)
        #pragma unroll
        for (int nt = 0; nt < 7; ++nt)
            #pragma unroll
            for (int r = 0; r < 4; ++r) acc[mt][nt][r] = 0.0f;

    const __bf16* ybase = y + (size_t)n * (H_DIM * W_DIM * CMID);

    // step s in [f..l]: kh = s>>1 (row h+kh-1), half = s&1 (channels half*96..)
    const int f = (h == 0)         ? 2 : 0;
    const int l = (h == H_DIM - 1) ? 3 : 5;

    uint4 r[6];
    // prefetch first step
    {
        int row = h + (f >> 1) - 1, half = f & 1;
        const uint4* src = (const uint4*)(ybase + (size_t)row * (W_DIM * CMID)) + half * 12;
        #pragma unroll
        for (int it = 0; it < 6; ++it) {
            int g = it * 256 + tid;
            if (g < 1344) {
                int px = g / 12, part = g - px * 12;
                r[it] = src[px * 24 + part];
            }
        }
    }

    int buf = 0;
    for (int s = f; s <= l; ++s) {
        // write staged data to LDS
        {
            #pragma unroll
            for (int it = 0; it < 6; ++it) {
                int g = it * 256 + tid;
                if (g < 1344) {
                    int px = g / 12, part = g - px * 12;
                    *(uint4*)&ybuf[buf][(px + 1) * YSTR + part * 8] = r[it];
                }
            }
        }
        // prefetch next step into regs (loads complete during compute below)
        if (s < l) {
            int row = h + ((s + 1) >> 1) - 1, half = (s + 1) & 1;
            const uint4* src = (const uint4*)(ybase + (size_t)row * (W_DIM * CMID)) + half * 12;
            #pragma unroll
            for (int it = 0; it < 6; ++it) {
                int g = it * 256 + tid;
                if (g < 1344) {
                    int px = g / 12, part = g - px * 12;
                    r[it] = src[px * 24 + part];
                }
            }
        }
        __syncthreads();

        const int kh   = s >> 1;
        const int half = s & 1;
        #pragma unroll
        for (int c3 = 0; c3 < 3; ++c3) {
            const int kc = c3 * 32 + quad * 8;           // within buffer
            const int ci = half * 96 + kc;               // global channel
            bf16x8 af[3][2];
            #pragma unroll
            for (int kw = 0; kw < 3; ++kw)
                #pragma unroll
                for (int mt = 0; mt < 2; ++mt)
                    af[kw][mt] = *(const bf16x8*)(
                        wr + (size_t)((kh * 3 + kw) * COUT + wid * 32 + mt * 16 + m) * CMID + ci);
            #pragma unroll
            for (int kw = 0; kw < 3; ++kw) {
                #pragma unroll
                for (int nt = 0; nt < 7; ++nt) {
                    bf16x8 bfrag = *(const bf16x8*)&ybuf[buf][(nt * 16 + m + kw) * YSTR + kc];
                    acc[0][nt] = __builtin_amdgcn_mfma_f32_16x16x32_bf16(
                        af[kw][0], bfrag, acc[0][nt], 0, 0, 0);
                    acc[1][nt] = __builtin_amdgcn_mfma_f32_16x16x32_bf16(
                        af[kw][1], bfrag, acc[1][nt], 0, 0, 0);
                }
            }
        }
        buf ^= 1;
    }

    // epilogue: D col = px (lane&15), row = quad*4+r -> co
    #pragma unroll
    for (int mt = 0; mt < 2; ++mt) {
        const int co0 = wid * 32 + mt * 16 + quad * 4;
        float bv[4];
        #pragma unroll
        for (int rr = 0; rr < 4; ++rr) bv[rr] = bias[co0 + rr];
        #pragma unroll
        for (int nt = 0; nt < 7; ++nt) {
            int j = nt * 16 + m;
            #pragma unroll
            for (int rr = 0; rr < 4; ++rr) {
                out[(((size_t)n * COUT + co0 + rr) * H_DIM + h) * W_DIM + j] =
                    acc[mt][nt][rr] + bv[rr];
            }
        }
    }
}

// ---------------------------------------------------------------
extern "C" void kernel_launch(void* const* d_in, const int* in_sizes, int n_in,
                              void* d_out, int out_size, void* d_ws, size_t ws_size,
                              hipStream_t stream) {
    const float* x      = (const float*)d_in[0];
    const float* w      = (const float*)d_in[1];
    const float* bias   = (const float*)d_in[2];
    const float* shifts = (const float*)d_in[3];
    float* out = (float*)d_out;

    __hip_bfloat16* y  = (__hip_bfloat16*)d_ws;                       // 77,070,336 B
    __hip_bfloat16* wr = (__hip_bfloat16*)((char*)d_ws + 77070336);   //    442,368 B

    repack_w_kernel<<<dim3((9 * COUT * CMID + 255) / 256), 256, 0, stream>>>(w, wr);
    shift_pow_kernel<<<dim3(H_DIM, NB), 256, 0, stream>>>(x, shifts, y);
    conv_kernel<<<dim3(H_DIM, NB), 256, 0, stream>>>(
        (const __bf16*)y, (const __bf16*)wr, bias, out);
}

// Round 4
// 290.522 us; speedup vs baseline: 1.4139x; 1.4139x over previous
//
#include <hip/hip_runtime.h>
#include <hip/hip_bf16.h>

// ---------- types ----------
typedef __bf16 bf16x8 __attribute__((ext_vector_type(8)));
typedef float  f32x4  __attribute__((ext_vector_type(4)));

#define H_DIM 112
#define W_DIM 112
#define CIN 64
#define CMID 192          // 3*64
#define COUT 128
#define NB 16

// ---------------------------------------------------------------
// async 16B global->LDS DMA. LDS dest must be WAVE-UNIFORM; HW adds lane*16.
// ---------------------------------------------------------------
__device__ __forceinline__ void dma16(const void* g, void* l) {
    __builtin_amdgcn_global_load_lds(
        (const __attribute__((address_space(1))) unsigned*)g,
        (__attribute__((address_space(3))) unsigned*)l, 16, 0, 0);
}

// ---------------------------------------------------------------
// Kernel A: repack weights [co][ci][kh][kw] fp32 -> [khw][co][ci] bf16
// ---------------------------------------------------------------
__global__ __launch_bounds__(256) void repack_w_kernel(
    const float* __restrict__ w, __hip_bfloat16* __restrict__ wr)
{
    int idx = blockIdx.x * 256 + threadIdx.x;
    if (idx < 9 * COUT * CMID) {
        int ci  = idx % CMID;
        int t   = idx / CMID;
        int co  = t % COUT;
        int khw = t / COUT;
        wr[idx] = __float2bfloat16(w[(co * CMID + ci) * 9 + khw]);
    }
}

// ---------------------------------------------------------------
// Kernel B: bilinear shift + powers -> y NHWC bf16  [16][112][112][192]
// Stage-then-compute: 32 channels per block (grid 112 x 2 x 16).
// Phase 1: coalesced float4 staging of 64 tap-rows into LDS (zeros if OOB row)
// Phase 2: bilinear + v,v^2,v^3 from LDS -> tile
// Phase 3: coalesced dword write-out
// ---------------------------------------------------------------
__global__ __launch_bounds__(256) void shift_pow_kernel(
    const float* __restrict__ x, const float* __restrict__ shifts,
    __hip_bfloat16* __restrict__ y)
{
    __shared__ __align__(16) float xs[64 * 116];               // 29,696 B
    __shared__ __align__(16) __hip_bfloat16 tile[112 * 104];   // 23,296 B
    __shared__ float4 prm[32];

    const int tid = threadIdx.x;
    const int h   = blockIdx.x;
    const int cb  = blockIdx.y * 32;
    const int n   = blockIdx.z;

    if (tid < 32) {
        float sx = shifts[2 * (cb + tid)]     * 4.0f;
        float sy = shifts[2 * (cb + tid) + 1] * 4.0f;
        float fx = floorf(sx), fy = floorf(sy);
        prm[tid] = make_float4(fx, fy, sx - fx, sy - fy);
    }
    __syncthreads();

    // ---- stage 64 tap-rows (32 ch x 2 taps) of 112 floats each ----
    #pragma unroll
    for (int k = 0; k < 7; ++k) {
        int i     = k * 256 + tid;          // 0..1791
        int rowid = i / 28;                 // 0..63
        int part  = i - rowid * 28;         // 0..27 (float4 chunks)
        int c = rowid >> 1, t = rowid & 1;
        int iy = (int)prm[c].y;
        int r  = h + iy + t;
        bool valid = (unsigned)r < (unsigned)H_DIM;
        int rr = min(max(r, 0), H_DIM - 1);
        float4 v = ((const float4*)(
            x + ((size_t)(n * CIN + cb + c) * H_DIM + rr) * W_DIM))[part];
        if (!valid) v = make_float4(0.f, 0.f, 0.f, 0.f);
        *(float4*)&xs[rowid * 116 + part * 4] = v;
    }
    __syncthreads();

    // ---- compute 32 ch x 112 px ----
    #pragma unroll
    for (int k = 0; k < 14; ++k) {
        int i  = k * 256 + tid;             // 0..3583
        int c  = i / 112;
        int px = i - c * 112;
        float4 p = prm[c];
        int ix = (int)p.x;
        float wx = p.z, wy = p.w;
        int q0 = px + ix, q1 = q0 + 1;
        float f0 = ((unsigned)q0 < (unsigned)W_DIM) ? 1.f : 0.f;
        float f1 = ((unsigned)q1 < (unsigned)W_DIM) ? 1.f : 0.f;
        int a0 = min(max(q0, 0), W_DIM - 1);
        int a1 = min(max(q1, 0), W_DIM - 1);
        const float* r0 = &xs[(2 * c) * 116];
        const float* r1 = &xs[(2 * c + 1) * 116];
        float top = (1.f - wx) * f0 * r0[a0] + wx * f1 * r0[a1];
        float bot = (1.f - wx) * f0 * r1[a0] + wx * f1 * r1[a1];
        float v  = (1.f - wy) * top + wy * bot;
        float v2 = v * v, v3 = v2 * v;
        __hip_bfloat16* tp = &tile[px * 104];
        tp[c]      = __float2bfloat16(v);
        tp[c + 32] = __float2bfloat16(v2);
        tp[c + 64] = __float2bfloat16(v3);
    }
    __syncthreads();

    // ---- write out: 112 px x 48 dwords (96 ch bf16) ----
    const unsigned* tl = (const unsigned*)tile;
    unsigned* yo = (unsigned*)(y + ((size_t)(n * H_DIM + h) * W_DIM) * CMID);
    const int cbd = cb >> 1;
    #pragma unroll
    for (int k = 0; k < 21; ++k) {
        int i  = k * 256 + tid;             // 0..5375
        int px = i / 48;
        int cp = i - px * 48;
        int chunk = cp >> 4, e = cp & 15;
        yo[px * 96 + chunk * 32 + cbd + e] = tl[px * 52 + cp];
    }
}

// ---------------------------------------------------------------
// Kernel C: implicit-GEMM 3x3 conv, bf16 MFMA 16x16x32.
// m97-style async pipeline: steps = (kh, half of 96 ch); double-buffered LDS
// staged via global_load_lds (width 16); ONE barrier per step, DMA for step
// s+1 issued before compute(s) so it drains (vmcnt) only at the step barrier.
// Block = 128 co x 112 px (one output row), wave = 32 co x 112 px (mt2, nt7).
// LDS slot stride 208 B (104 elems): 192 B data + 16 B pad (pad lane masked).
// ---------------------------------------------------------------
#define YSTR_E 104                  // elements per px slot (208 B)
#define BUF_E  12288                // 24,576 B per buffer (covers DMA overrun)

__global__ __launch_bounds__(256, 3) void conv_kernel(
    const __bf16* __restrict__ y,    // [16][112][112][192]
    const __bf16* __restrict__ wr,   // [9][128][192]
    const float* __restrict__ bias,
    float* __restrict__ out)         // [16][128][112][112]
{
    __shared__ __align__(16) __bf16 ybuf[2][BUF_E];   // 49,152 B

    const int tid  = threadIdx.x;
    const int lane = tid & 63;
    const int wid  = tid >> 6;
    const int m    = lane & 15;
    const int quad = lane >> 4;

    const int h = blockIdx.x;
    const int n = blockIdx.y;

    // zero halo slots (slot 0 = px -1, slot 113 = px 112) of both buffers
    if (tid < 208) {
        int b    = tid >= 104;
        int r    = tid - b * 104;
        int slot = (r >= 52) ? 113 : 0;
        int dw   = (r >= 52) ? r - 52 : r;
        ((unsigned*)&ybuf[b][0])[slot * 52 + dw] = 0u;
    }

    // per-lane DMA source-offset table: chunk t = 4*j + wid, LDS byte
    // o = 208 + 1024*t + 16*lane -> slot = o/208, rem = o%208.
    // valid data lane iff rem<192 and slot in [1,112]; global byte offset
    // within (row,half) = (slot-1)*384 + rem.
    int dj[6];
    #pragma unroll
    for (int j = 0; j < 6; ++j) {
        int t = 4 * j + wid;
        int o = 208 + 1024 * t + 16 * lane;
        int slot = o / 208;
        int rem  = o - slot * 208;
        dj[j] = (t < 23 && rem < 192 && slot <= 112)
                    ? ((slot - 1) * 384 + rem) : -1;
    }

    f32x4 acc[2][7];
    #pragma unroll
    for (int mt = 0; mt < 2; ++mt)
        #pragma unroll
        for (int nt = 0; nt < 7; ++nt)
            #pragma unroll
            for (int r = 0; r < 4; ++r) acc[mt][nt][r] = 0.0f;

    const char* ybase = (const char*)y + (size_t)n * (H_DIM * W_DIM * CMID * 2);

    // step s: kh = s>>1 (row h+kh-1), half = s&1 (channels half*96 ..)
    const int f = (h == 0)         ? 2 : 0;
    const int l = (h == H_DIM - 1) ? 3 : 5;

    // ---- stage step f into buffer 0 ----
    {
        int row = h + (f >> 1) - 1, half = f & 1;
        const char* src = ybase + (size_t)row * (W_DIM * CMID * 2) + half * 192;
        char* lb = (char*)&ybuf[0][0];
        #pragma unroll
        for (int j = 0; j < 6; ++j) {
            int t = 4 * j + wid;
            if (dj[j] >= 0) dma16(src + dj[j], lb + 208 + 1024 * t);
        }
    }
    __syncthreads();   // drains first stage

    int buf = 0;
    for (int s = f; s <= l; ++s) {
        // issue async stage of step s+1 into the other buffer
        if (s < l) {
            int row = h + ((s + 1) >> 1) - 1, half = (s + 1) & 1;
            const char* src = ybase + (size_t)row * (W_DIM * CMID * 2) + half * 192;
            char* lb = (char*)&ybuf[buf ^ 1][0];
            #pragma unroll
            for (int j = 0; j < 6; ++j) {
                int t = 4 * j + wid;
                if (dj[j] >= 0) dma16(src + dj[j], lb + 208 + 1024 * t);
            }
        }

        // compute step s from ybuf[buf]
        const int kh = s >> 1, half = s & 1;
        const __bf16* bufp = &ybuf[buf][0];
        #pragma unroll
        for (int c3 = 0; c3 < 3; ++c3) {
            const int kc = c3 * 32 + quad * 8;        // elem offset in slot
            const int ci = half * 96 + kc;            // global channel
            bf16x8 af[3][2];
            #pragma unroll
            for (int kw = 0; kw < 3; ++kw)
                #pragma unroll
                for (int mt = 0; mt < 2; ++mt)
                    af[kw][mt] = *(const bf16x8*)(
                        wr + (size_t)((kh * 3 + kw) * COUT + wid * 32 + mt * 16 + m) * CMID + ci);
            #pragma unroll
            for (int kw = 0; kw < 3; ++kw) {
                #pragma unroll
                for (int nt = 0; nt < 7; ++nt) {
                    bf16x8 bfrag = *(const bf16x8*)&bufp[(nt * 16 + m + kw) * YSTR_E + kc];
                    acc[0][nt] = __builtin_amdgcn_mfma_f32_16x16x32_bf16(
                        af[kw][0], bfrag, acc[0][nt], 0, 0, 0);
                    acc[1][nt] = __builtin_amdgcn_mfma_f32_16x16x32_bf16(
                        af[kw][1], bfrag, acc[1][nt], 0, 0, 0);
                }
            }
        }
        __syncthreads();   // drains stage(s+1) DMA + protects buffer reuse
        buf ^= 1;
    }

    // epilogue: D col = px (lane&15), row = quad*4+r -> co
    #pragma unroll
    for (int mt = 0; mt < 2; ++mt) {
        const int co0 = wid * 32 + mt * 16 + quad * 4;
        float bv[4];
        #pragma unroll
        for (int rr = 0; rr < 4; ++rr) bv[rr] = bias[co0 + rr];
        #pragma unroll
        for (int nt = 0; nt < 7; ++nt) {
            int j = nt * 16 + m;
            #pragma unroll
            for (int rr = 0; rr < 4; ++rr) {
                out[(((size_t)n * COUT + co0 + rr) * H_DIM + h) * W_DIM + j] =
                    acc[mt][nt][rr] + bv[rr];
            }
        }
    }
}

// ---------------------------------------------------------------
extern "C" void kernel_launch(void* const* d_in, const int* in_sizes, int n_in,
                              void* d_out, int out_size, void* d_ws, size_t ws_size,
                              hipStream_t stream) {
    const float* x      = (const float*)d_in[0];
    const float* w      = (const float*)d_in[1];
    const float* bias   = (const float*)d_in[2];
    const float* shifts = (const float*)d_in[3];
    float* out = (float*)d_out;

    __hip_bfloat16* y  = (__hip_bfloat16*)d_ws;                       // 77,070,336 B
    __hip_bfloat16* wr = (__hip_bfloat16*)((char*)d_ws + 77070336);   //    442,368 B

    repack_w_kernel<<<dim3((9 * COUT * CMID + 255) / 256), 256, 0, stream>>>(w, wr);
    shift_pow_kernel<<<dim3(H_DIM, 2, NB), 256, 0, stream>>>(x, shifts, y);
    conv_kernel<<<dim3(H_DIM, NB), 256, 0, stream>>>(
        (const __bf16*)y, (const __bf16*)wr, bias, out);
}